// Round 2
// baseline (1358.964 us; speedup 1.0000x reference)
//
#include <hip/hip_runtime.h>

#define T_LEN 2048
#define C_LEN 8192
#define NHV   32
#define TILE  32
#define XSS   292   // padded LDS row stride (floats); 292 % 32 == 4

__device__ __forceinline__ float frcp(float x) { return __builtin_amdgcn_rcpf(x); }
__device__ __forceinline__ float sigm(float x) { return frcp(1.f + __expf(-x)); }

__global__ __launch_bounds__(256) void gdn_fused(
    const float* __restrict__ xin,   // [B,T,C]
    const float* __restrict__ bin,   // [B,T,HV]
    const float* __restrict__ ain,   // [B,T,HV]
    const float* __restrict__ win,   // [C,4]
    const float* __restrict__ dtb,   // [HV]
    const float* __restrict__ alg,   // [HV]
    float* __restrict__ out)         // [B,T,HV*DV]
{
  const int tid   = threadIdx.x;
  const int bx    = blockIdx.x;
  const int chunk = bx & 3;          // 4 column chunks of 32
  const int hv    = (bx >> 2) & 31;  // value head
  const int bb    = bx >> 7;         // batch
  const int hk    = hv >> 1;         // GQA: key head

  const int qch0 = hk * 128;                       // q channels [0,2048)
  const int kch0 = 2048 + hk * 128;                // k channels [2048,4096)
  const int vch0 = 4096 + hv * 128 + chunk * 32;   // v channels [4096,8192)

  __shared__ __align__(16) float  xs[TILE][XSS];   // conv+silu tile: q[0,128) k[128,256) v[256,288)
  __shared__ __align__(16) float4 wc[288];         // conv weights for this block's channels
  __shared__ float s_eg[TILE], s_beta[TILE], s_qk[TILE], s_rq[TILE], s_rk[TILE];

  for (int i = tid; i < 288; i += 256) {
    int gch = (i < 128) ? (qch0 + i) : (i < 256) ? (kch0 + i - 128) : (vch0 + i - 256);
    wc[i] = *(const float4*)(win + (size_t)gch * 4);
  }

  const int lane = tid & 63;
  const int wv   = tid >> 6;
  const int rg   = lane & 7;              // row-group 0..7
  const int col  = wv * 8 + (lane >> 3);  // column within block, 0..31
  const int rg4  = rg * 4;

  const float dtbv = dtb[hv];
  const float nA   = -__expf(alg[hv]);

  // state: S[ii*4+j] <-> row (ii*32 + rg*4 + j), this thread's column
  float S[16];
#pragma unroll
  for (int m = 0; m < 16; ++m) S[m] = 0.f;

  const float* xb = xin + (size_t)bb * T_LEN * C_LEN;
  float* op = out + (size_t)bb * T_LEN * 4096 + hv * 128 + chunk * 32 + col;

  for (int t0 = 0; t0 < T_LEN; t0 += TILE) {
    __syncthreads();  // previous tile's scan readers done (also wc ready on first iter)

    // ---- causal depthwise conv + SiLU -> xs ----
    for (int idx = tid; idx < TILE * 72; idx += 256) {
      int row = idx / 72;
      int c4  = idx - row * 72;
      int gch = (c4 < 32) ? (qch0 + c4 * 4)
              : (c4 < 64) ? (kch0 + (c4 - 32) * 4)
                          : (vch0 + (c4 - 64) * 4);
      int r = t0 + row - 3;
      const float* gp = xb + (size_t)r * C_LEN + gch;
      float4 a0 = (r     >= 0) ? *(const float4*)(gp)             : make_float4(0,0,0,0);
      float4 a1 = (r + 1 >= 0) ? *(const float4*)(gp + C_LEN)     : make_float4(0,0,0,0);
      float4 a2 = (r + 2 >= 0) ? *(const float4*)(gp + 2 * C_LEN) : make_float4(0,0,0,0);
      float4 a3 =                *(const float4*)(gp + 3 * C_LEN);  // r+3 = t0+row >= 0
      float4 w0 = wc[c4 * 4], w1 = wc[c4 * 4 + 1], w2 = wc[c4 * 4 + 2], w3 = wc[c4 * 4 + 3];
      float4 o4;
      o4.x = a0.x * w0.x + a1.x * w0.y + a2.x * w0.z + a3.x * w0.w;
      o4.y = a0.y * w1.x + a1.y * w1.y + a2.y * w1.z + a3.y * w1.w;
      o4.z = a0.z * w2.x + a1.z * w2.y + a2.z * w2.z + a3.z * w2.w;
      o4.w = a0.w * w3.x + a1.w * w3.y + a2.w * w3.z + a3.w * w3.w;
      o4.x *= sigm(o4.x); o4.y *= sigm(o4.y); o4.z *= sigm(o4.z); o4.w *= sigm(o4.w);
      *(float4*)&xs[row][c4 * 4] = o4;
    }
    // ---- beta / exp(g) ----
    if (tid < TILE) {
      int tg = t0 + tid;
      size_t boff = ((size_t)bb * T_LEN + tg) * NHV + hv;
      s_beta[tid] = sigm(bin[boff]);
      float x  = ain[boff] + dtbv;
      float sp = fmaxf(x, 0.f) + log1pf(__expf(-fabsf(x)));   // softplus
      s_eg[tid] = __expf(nA * sp);
    }
    __syncthreads();

    // ---- l2-norm factors + q.k dot per row ----
    {
      int ttn = tid >> 3, l8 = tid & 7;   // 32 rows x 8 lanes
      float sq = 0.f, sk = 0.f, pr = 0.f;
#pragma unroll
      for (int m = 0; m < 16; ++m) {
        int cc = m * 8 + l8;              // strided -> <=2-way LDS conflict
        float aq = xs[ttn][cc];
        float ak = xs[ttn][128 + cc];
        sq += aq * aq; sk += ak * ak; pr += aq * ak;
      }
      sq += __shfl_xor(sq, 1); sq += __shfl_xor(sq, 2); sq += __shfl_xor(sq, 4);
      sk += __shfl_xor(sk, 1); sk += __shfl_xor(sk, 2); sk += __shfl_xor(sk, 4);
      pr += __shfl_xor(pr, 1); pr += __shfl_xor(pr, 2); pr += __shfl_xor(pr, 4);
      if (l8 == 0) {
        float rq = rsqrtf(sq + 1e-6f) * 0.08838834764831845f;  // includes DK^-0.5
        float rk = rsqrtf(sk + 1e-6f);
        s_rq[ttn] = rq; s_rk[ttn] = rk; s_qk[ttn] = pr * rq * rk;
      }
    }
    __syncthreads();

    // ---- scale q,k in LDS ----
    for (int idx = tid; idx < TILE * 64; idx += 256) {
      int row = idx >> 6, c4 = idx & 63;
      float f = (c4 < 32) ? s_rq[row] : s_rk[row];
      float4* p = (float4*)&xs[row][c4 * 4];
      float4 v = *p;
      v.x *= f; v.y *= f; v.z *= f; v.w *= f;
      *p = v;
    }
    __syncthreads();

    // ---- 32 sequential scan steps ----
#pragma unroll 2
    for (int tt = 0; tt < TILE; ++tt) {
      const float* xr = &xs[tt][0];
      float4 q0 = *(const float4*)(xr +       rg4);
      float4 q1 = *(const float4*)(xr +  32 + rg4);
      float4 q2 = *(const float4*)(xr +  64 + rg4);
      float4 q3 = *(const float4*)(xr +  96 + rg4);
      float4 k0 = *(const float4*)(xr + 128 + rg4);
      float4 k1 = *(const float4*)(xr + 160 + rg4);
      float4 k2 = *(const float4*)(xr + 192 + rg4);
      float4 k3 = *(const float4*)(xr + 224 + rg4);

      float dk = k0.x*S[0]  + k0.y*S[1]  + k0.z*S[2]  + k0.w*S[3]
               + k1.x*S[4]  + k1.y*S[5]  + k1.z*S[6]  + k1.w*S[7]
               + k2.x*S[8]  + k2.y*S[9]  + k2.z*S[10] + k2.w*S[11]
               + k3.x*S[12] + k3.y*S[13] + k3.z*S[14] + k3.w*S[15];
      float dq = q0.x*S[0]  + q0.y*S[1]  + q0.z*S[2]  + q0.w*S[3]
               + q1.x*S[4]  + q1.y*S[5]  + q1.z*S[6]  + q1.w*S[7]
               + q2.x*S[8]  + q2.y*S[9]  + q2.z*S[10] + q2.w*S[11]
               + q3.x*S[12] + q3.y*S[13] + q3.z*S[14] + q3.w*S[15];

      dk += __shfl_xor(dk, 1); dk += __shfl_xor(dk, 2); dk += __shfl_xor(dk, 4);
      dq += __shfl_xor(dq, 1); dq += __shfl_xor(dq, 2); dq += __shfl_xor(dq, 4);

      float eg    = s_eg[tt];
      float delta = (xr[256 + col] - eg * dk) * s_beta[tt];
      float o     = eg * dq + s_qk[tt] * delta;

      S[0]  = eg*S[0]  + k0.x*delta;  S[1]  = eg*S[1]  + k0.y*delta;
      S[2]  = eg*S[2]  + k0.z*delta;  S[3]  = eg*S[3]  + k0.w*delta;
      S[4]  = eg*S[4]  + k1.x*delta;  S[5]  = eg*S[5]  + k1.y*delta;
      S[6]  = eg*S[6]  + k1.z*delta;  S[7]  = eg*S[7]  + k1.w*delta;
      S[8]  = eg*S[8]  + k2.x*delta;  S[9]  = eg*S[9]  + k2.y*delta;
      S[10] = eg*S[10] + k2.z*delta;  S[11] = eg*S[11] + k2.w*delta;
      S[12] = eg*S[12] + k3.x*delta;  S[13] = eg*S[13] + k3.y*delta;
      S[14] = eg*S[14] + k3.z*delta;  S[15] = eg*S[15] + k3.w*delta;

      if (rg == 0) op[(size_t)(t0 + tt) * 4096] = o;
    }
  }
}

extern "C" void kernel_launch(void* const* d_in, const int* in_sizes, int n_in,
                              void* d_out, int out_size, void* d_ws, size_t ws_size,
                              hipStream_t stream) {
  (void)in_sizes; (void)n_in; (void)out_size; (void)d_ws; (void)ws_size;
  gdn_fused<<<dim3(256), dim3(256), 0, stream>>>(
      (const float*)d_in[0], (const float*)d_in[1], (const float*)d_in[2],
      (const float*)d_in[3], (const float*)d_in[4], (const float*)d_in[5],
      (float*)d_out);
}

// Round 4
// 1276.610 us; speedup vs baseline: 1.0645x; 1.0645x over previous
//
#include <hip/hip_runtime.h>

#define T_LEN 2048
#define C_LEN 8192
#define NHV   32
#define TILE  32
#define NCOL  16    // columns per block
#define XSS   276   // xs row stride (floats): q[0,128) k[128,256) v[256,272) + pad
#define OTS   33    // opT row stride (floats)

__device__ __forceinline__ float frcp(float x) { return __builtin_amdgcn_rcpf(x); }
__device__ __forceinline__ float sigm(float x) { return frcp(1.f + __expf(-x)); }

__global__ __launch_bounds__(256) void gdn_fused(
    const float* __restrict__ xin,   // [B,T,C]
    const float* __restrict__ bin,   // [B,T,HV]
    const float* __restrict__ ain,   // [B,T,HV]
    const float* __restrict__ win,   // [C,4]
    const float* __restrict__ dtb,   // [HV]
    const float* __restrict__ alg,   // [HV]
    float* __restrict__ out)         // [B,T,HV*DV]
{
  const int tid   = threadIdx.x;
  const int bx    = blockIdx.x;
  const int chunk = bx & 7;          // 8 column chunks of 16
  const int hv    = (bx >> 3) & 31;  // value head
  const int bb    = bx >> 8;         // batch
  const int hk    = hv >> 1;         // GQA: key head

  const int qch0 = hk * 128;                       // q channels
  const int kch0 = 2048 + hk * 128;                // k channels
  const int vch0 = 4096 + hv * 128 + chunk * NCOL; // v channels (16)

  __shared__ __align__(16) float  xs[TILE][XSS];
  __shared__ __align__(16) float4 wc[272];         // conv weights (68 groups of 4ch)
  __shared__ float  opT[256 * OTS];                // o partials, transposed [rowpart][tt]
  __shared__ float2 s_gb[TILE];                    // {exp(g), beta}
  __shared__ float  s_rq[TILE], s_rk[TILE];

  for (int i = tid; i < 272; i += 256) {
    int gch = (i < 128) ? (qch0 + i) : (i < 256) ? (kch0 + i - 128) : (vch0 + i - 256);
    wc[i] = *(const float4*)(win + (size_t)gch * 4);
  }

  const int lane = tid & 63;
  const int wv   = tid >> 6;
  const int rg   = lane & 15;             // row-group 0..15 (16 lanes per column)
  const int col  = wv * 4 + (lane >> 4);  // column within block, 0..15
  const int rg4  = rg * 4;

  const float dtbv = dtb[hv];
  const float nA   = -__expf(alg[hv]);

  // state: S[seg*4+j] <-> row (seg*64 + rg*4 + j), this thread's column
  float S[8];
#pragma unroll
  for (int m = 0; m < 8; ++m) S[m] = 0.f;

  const float* xb  = xin + (size_t)bb * T_LEN * C_LEN;
  float*       op  = out + (size_t)bb * T_LEN * 4096 + hv * 128 + chunk * NCOL;
  float*       opw = &opT[(wv * 64 + lane) * OTS];

  for (int t0 = 0; t0 < T_LEN; t0 += TILE) {
    __syncthreads();  // previous tile fully consumed (and wc ready on first iter)

    // ---- causal depthwise conv + SiLU -> xs ----
    for (int idx = tid; idx < TILE * 68; idx += 256) {
      int row = idx / 68;
      int c4  = idx - row * 68;
      int gch = (c4 < 32) ? (qch0 + c4 * 4)
              : (c4 < 64) ? (kch0 + (c4 - 32) * 4)
                          : (vch0 + (c4 - 64) * 4);
      int r = t0 + row - 3;
      const float* gp = xb + (size_t)r * C_LEN + gch;
      float4 a0 = (r     >= 0) ? *(const float4*)(gp)             : make_float4(0,0,0,0);
      float4 a1 = (r + 1 >= 0) ? *(const float4*)(gp + C_LEN)     : make_float4(0,0,0,0);
      float4 a2 = (r + 2 >= 0) ? *(const float4*)(gp + 2 * C_LEN) : make_float4(0,0,0,0);
      float4 a3 =                *(const float4*)(gp + 3 * C_LEN);  // r+3 = t0+row >= 0
      float4 w0 = wc[c4 * 4], w1 = wc[c4 * 4 + 1], w2 = wc[c4 * 4 + 2], w3 = wc[c4 * 4 + 3];
      float4 o4;
      o4.x = a0.x * w0.x + a1.x * w0.y + a2.x * w0.z + a3.x * w0.w;
      o4.y = a0.y * w1.x + a1.y * w1.y + a2.y * w1.z + a3.y * w1.w;
      o4.z = a0.z * w2.x + a1.z * w2.y + a2.z * w2.z + a3.z * w2.w;
      o4.w = a0.w * w3.x + a1.w * w3.y + a2.w * w3.z + a3.w * w3.w;
      o4.x *= sigm(o4.x); o4.y *= sigm(o4.y); o4.z *= sigm(o4.z); o4.w *= sigm(o4.w);
      *(float4*)&xs[row][c4 * 4] = o4;
    }
    // ---- beta / exp(g) ----
    if (tid < TILE) {
      int tg = t0 + tid;
      size_t boff = ((size_t)bb * T_LEN + tg) * NHV + hv;
      float  bt = sigm(bin[boff]);
      float  x  = ain[boff] + dtbv;
      float  sp = fmaxf(x, 0.f) + log1pf(__expf(-fabsf(x)));   // softplus
      s_gb[tid] = make_float2(__expf(nA * sp), bt);
    }
    __syncthreads();

    // ---- l2-norm factors per row ----
    {
      int ttn = tid >> 3, l8 = tid & 7;   // 32 rows x 8 lanes
      float sq = 0.f, sk = 0.f;
#pragma unroll
      for (int m = 0; m < 16; ++m) {
        int cc = m * 8 + l8;
        float aq = xs[ttn][cc];
        float ak = xs[ttn][128 + cc];
        sq += aq * aq; sk += ak * ak;
      }
      sq += __shfl_xor(sq, 1); sq += __shfl_xor(sq, 2); sq += __shfl_xor(sq, 4);
      sk += __shfl_xor(sk, 1); sk += __shfl_xor(sk, 2); sk += __shfl_xor(sk, 4);
      if (l8 == 0) {
        s_rq[ttn] = rsqrtf(sq + 1e-6f) * 0.08838834764831845f;  // includes DK^-0.5
        s_rk[ttn] = rsqrtf(sk + 1e-6f);
      }
    }
    __syncthreads();

    // ---- scale q,k in LDS ----
    for (int idx = tid; idx < TILE * 64; idx += 256) {
      int row = idx >> 6, c4 = idx & 63;
      float f = (c4 < 32) ? s_rq[row] : s_rk[row];
      float4* p = (float4*)&xs[row][c4 * 4];
      float4 v = *p;
      v.x *= f; v.y *= f; v.z *= f; v.w *= f;
      *p = v;
    }
    __syncthreads();

    // ---- 32 sequential scan steps ----
#pragma unroll 2
    for (int tt = 0; tt < TILE; ++tt) {
      const float* xr = &xs[tt][0];
      float4 k0 = *(const float4*)(xr + 128 + rg4);
      float4 k1 = *(const float4*)(xr + 192 + rg4);
      float  vv = xr[256 + col];
      float4 q0 = *(const float4*)(xr +       rg4);
      float4 q1 = *(const float4*)(xr +  64 + rg4);

      float dk = k0.x*S[0] + k0.y*S[1] + k0.z*S[2] + k0.w*S[3]
               + k1.x*S[4] + k1.y*S[5] + k1.z*S[6] + k1.w*S[7];
      dk += __shfl_xor(dk, 1); dk += __shfl_xor(dk, 2);
      dk += __shfl_xor(dk, 4); dk += __shfl_xor(dk, 8);

      float2 gb    = s_gb[tt];
      float  eg    = gb.x;
      float  delta = (vv - eg * dk) * gb.y;

      S[0] = eg*S[0] + k0.x*delta;  S[1] = eg*S[1] + k0.y*delta;
      S[2] = eg*S[2] + k0.z*delta;  S[3] = eg*S[3] + k0.w*delta;
      S[4] = eg*S[4] + k1.x*delta;  S[5] = eg*S[5] + k1.y*delta;
      S[6] = eg*S[6] + k1.z*delta;  S[7] = eg*S[7] + k1.w*delta;

      float o = q0.x*S[0] + q0.y*S[1] + q0.z*S[2] + q0.w*S[3]
              + q1.x*S[4] + q1.y*S[5] + q1.z*S[6] + q1.w*S[7];
      opw[tt] = o;   // per-thread partial of q . S_new
    }
    __syncthreads();

    // ---- batch o-reduction + store ----
    {
      int ttb = tid & 31, colb = tid >> 5;          // colb 0..7
#pragma unroll
      for (int it = 0; it < 2; ++it) {
        int cc = colb + it * 8;
        const float* pp = &opT[(cc * 16) * OTS + ttb];
        float s = 0.f;
#pragma unroll
        for (int i = 0; i < 16; ++i) s += pp[i * OTS];
        op[(size_t)(t0 + ttb) * 4096 + cc] = s;
      }
    }
  }
}

extern "C" void kernel_launch(void* const* d_in, const int* in_sizes, int n_in,
                              void* d_out, int out_size, void* d_ws, size_t ws_size,
                              hipStream_t stream) {
  (void)in_sizes; (void)n_in; (void)out_size; (void)d_ws; (void)ws_size;
  gdn_fused<<<dim3(512), dim3(256), 0, stream>>>(
      (const float*)d_in[0], (const float*)d_in[1], (const float*)d_in[2],
      (const float*)d_in[3], (const float*)d_in[4], (const float*)d_in[5],
      (float*)d_out);
}

// Round 7
// 948.656 us; speedup vs baseline: 1.4325x; 1.3457x over previous
//
#include <hip/hip_runtime.h>

#define T_LEN 2048
#define C_LEN 8192
#define NHV   32

__device__ __forceinline__ float frcp(float x) { return __builtin_amdgcn_rcpf(x); }
__device__ __forceinline__ float sigm(float x) { return frcp(1.f + __expf(-x)); }

// ============================ NEW 3-KERNEL PATH ============================
// ws layout: xqk [b][hk][t][256] floats (q 0..127 scaled+normed, k 128..255 normed)
//            = 2*16*2048*256*4 = 67,108,864 bytes
//            xgb [b][hv][t] float2 {exp(g), beta} at offset 67,108,864 (1 MB)
#define WS_XQK_BYTES 67108864ULL
#define WS_NEED      (WS_XQK_BYTES + 2ULL*NHV*T_LEN*8ULL)

struct F8 { float v[8]; };

__device__ __forceinline__ F8 ld8(const float* p, bool pred) {
  F8 r;
  if (pred) {
    float4 a = *(const float4*)p, b = *(const float4*)(p + 4);
    r.v[0]=a.x; r.v[1]=a.y; r.v[2]=a.z; r.v[3]=a.w;
    r.v[4]=b.x; r.v[5]=b.y; r.v[6]=b.z; r.v[7]=b.w;
  } else {
#pragma unroll
    for (int i = 0; i < 8; ++i) r.v[i] = 0.f;
  }
  return r;
}

// K1: conv+SiLU+l2norm(+q scale) for q/k channels, written once.
// grid 1024: qk = gx&1 (0=q,1=k), tc = (gx>>1)&255 (8-t chunk), b = gx>>9
__global__ __launch_bounds__(256, 4) void k1_prep(
    const float* __restrict__ xin, const float* __restrict__ win,
    float* __restrict__ xqk)
{
  const int gx  = blockIdx.x;
  const int qk  = gx & 1, tc = (gx >> 1) & 255, b = gx >> 9;
  const int tid = threadIdx.x;
  const int hs  = tid >> 4;            // head 0..15
  const int lo  = (tid & 15) * 8;      // channel offset within head
  const int ch  = qk * 2048 + hs * 128 + lo;

  const float* xb = xin + (size_t)b * T_LEN * C_LEN + ch;

  // weights transposed: wt[j].v[c] = win[(ch+c)*4 + j]
  F8 wt0, wt1, wt2, wt3;
#pragma unroll
  for (int c = 0; c < 8; ++c) {
    float4 w = *(const float4*)(win + (size_t)(ch + c) * 4);
    wt0.v[c] = w.x; wt1.v[c] = w.y; wt2.v[c] = w.z; wt3.v[c] = w.w;
  }

  const int t0 = tc * 8;
  F8 r0 = ld8(xb + (size_t)(t0 - 3) * C_LEN, t0 >= 3);
  F8 r1 = ld8(xb + (size_t)(t0 - 2) * C_LEN, t0 >= 2);
  F8 r2 = ld8(xb + (size_t)(t0 - 1) * C_LEN, t0 >= 1);

  float* outp = xqk + ((size_t)(b * 16 + hs) * T_LEN) * 256 + qk * 128 + lo;
  const float qscale = qk ? 1.f : 0.08838834764831845f;

#pragma unroll
  for (int dt = 0; dt < 8; ++dt) {
    const int t = t0 + dt;
    F8 cur = ld8(xb + (size_t)t * C_LEN, true);
    F8 y; float sq = 0.f;
#pragma unroll
    for (int c = 0; c < 8; ++c) {
      float s = wt0.v[c]*r0.v[c] + wt1.v[c]*r1.v[c] + wt2.v[c]*r2.v[c] + wt3.v[c]*cur.v[c];
      s = s * sigm(s);
      y.v[c] = s; sq += s * s;
    }
    sq += __shfl_xor(sq, 1); sq += __shfl_xor(sq, 2);
    sq += __shfl_xor(sq, 4); sq += __shfl_xor(sq, 8);
    const float rn = rsqrtf(sq + 1e-6f) * qscale;
    float4 oa, ob;
    oa.x=y.v[0]*rn; oa.y=y.v[1]*rn; oa.z=y.v[2]*rn; oa.w=y.v[3]*rn;
    ob.x=y.v[4]*rn; ob.y=y.v[5]*rn; ob.z=y.v[6]*rn; ob.w=y.v[7]*rn;
    float* op = outp + (size_t)t * 256;
    *(float4*)op = oa; *(float4*)(op + 4) = ob;
    r0 = r1; r1 = r2; r2 = cur;
  }
}

// K1b: {exp(g), beta} per (b,hv,t). grid 512 x 256.
__global__ __launch_bounds__(256) void k1b_gate(
    const float* __restrict__ bin, const float* __restrict__ ain,
    const float* __restrict__ dtb, const float* __restrict__ alg,
    float2* __restrict__ xgb)
{
  const int idx = blockIdx.x * 256 + threadIdx.x;   // = ((b*32+hv)*2048 + t)
  const int b = idx >> 16, hv = (idx >> 11) & 31, t = idx & 2047;
  const size_t src = ((size_t)(b * T_LEN + t)) * NHV + hv;
  const float bt = sigm(bin[src]);
  const float x  = ain[src] + dtb[hv];
  const float sp = fmaxf(x, 0.f) + log1pf(__expf(-fabsf(x)));
  xgb[idx] = make_float2(__expf(-__expf(alg[hv]) * sp), bt);
}

// K2: the scan. 32 lanes/column (S[4]/thread), 8 cols/block, 1024 blocks.
// grid: chunk = bx&15, hv = (bx>>4)&31, bb = bx>>9
__global__ __launch_bounds__(256, 4) void k2_scan(
    const float* __restrict__ xin, const float* __restrict__ win,
    const float* __restrict__ xqk, const float2* __restrict__ xgb,
    float* __restrict__ out)
{
  const int bx = blockIdx.x;
  const int chunk = bx & 15, hv = (bx >> 4) & 31, bb = bx >> 9;
  const int hk = hv >> 1;
  const int tid = threadIdx.x;
  const int i  = tid & 31;    // row group: rows i*4 .. i*4+3
  const int cc = tid >> 5;    // column 0..7
  const int vch = 4096 + hv * 128 + chunk * 8 + cc;

  __shared__ float opT[32 * 257];   // [i][tt*8+cc], stride 257
  __shared__ float vs[32][8];

  const float*  qkp = xqk + ((size_t)(bb * 16 + hk) * T_LEN) * 256;
  const float2* gbp = xgb + ((size_t)(bb * NHV + hv)) * T_LEN;
  const float*  xvb = xin + (size_t)bb * T_LEN * C_LEN + vch;
  const float4  wv  = *(const float4*)(win + (size_t)vch * 4);
  float* outp = out + (size_t)bb * T_LEN * 4096 + hv * 128 + chunk * 8;

  float S0 = 0.f, S1 = 0.f, S2 = 0.f, S3 = 0.f;

  for (int t0 = 0; t0 < T_LEN; t0 += 32) {
    // ---- stage v (depthwise conv + SiLU), thread (i,cc) -> vs[i][cc] ----
    {
      const int t = t0 + i;
      const float* p = xvb + (size_t)t * C_LEN;
      float a0 = (t >= 3) ? p[-3 * C_LEN] : 0.f;
      float a1 = (t >= 2) ? p[-2 * C_LEN] : 0.f;
      float a2 = (t >= 1) ? p[-1 * C_LEN] : 0.f;
      float a3 = p[0];
      float s = wv.x*a0 + wv.y*a1 + wv.z*a2 + wv.w*a3;
      vs[i][cc] = s * sigm(s);
    }
    __syncthreads();  // vs ready; previous opT reduce finished

    const float* qrow = qkp + (size_t)t0 * 256;
#pragma unroll 4
    for (int tt = 0; tt < 32; ++tt) {
      const float4 kf = *(const float4*)(qrow + 128 + i * 4);
      const float4 qf = *(const float4*)(qrow + i * 4);
      const float  vv = vs[tt][cc];
      const float2 gb = gbp[t0 + tt];

      float dk = kf.x*S0 + kf.y*S1 + kf.z*S2 + kf.w*S3;
      dk += __shfl_xor(dk, 1); dk += __shfl_xor(dk, 2);
      dk += __shfl_xor(dk, 4); dk += __shfl_xor(dk, 8);
      dk += __shfl_xor(dk, 16);

      const float eg    = gb.x;
      const float delta = (vv - eg * dk) * gb.y;

      S0 = eg*S0 + kf.x*delta; S1 = eg*S1 + kf.y*delta;
      S2 = eg*S2 + kf.z*delta; S3 = eg*S3 + kf.w*delta;

      const float o = qf.x*S0 + qf.y*S1 + qf.z*S2 + qf.w*S3;
      opT[i * 257 + tt * 8 + cc] = o;
      qrow += 256;
    }
    __syncthreads();

    // ---- reduce 32 row-partials per output; tid = tt*8+cc ----
    {
      float s = 0.f;
#pragma unroll
      for (int r = 0; r < 32; ++r) s += opT[r * 257 + tid];
      const int tt2 = tid >> 3, c2 = tid & 7;
      outp[(size_t)(t0 + tt2) * 4096 + c2] = s;
    }
  }
}

// ============================ FALLBACK (v2, passed @1277us) ============================
#define TILE  32
#define NCOL  16
#define XSS   276
#define OTS   33

__global__ __launch_bounds__(256) void gdn_fused(
    const float* __restrict__ xin, const float* __restrict__ bin,
    const float* __restrict__ ain, const float* __restrict__ win,
    const float* __restrict__ dtb, const float* __restrict__ alg,
    float* __restrict__ out)
{
  const int tid   = threadIdx.x;
  const int bx    = blockIdx.x;
  const int chunk = bx & 7;
  const int hv    = (bx >> 3) & 31;
  const int bb    = bx >> 8;
  const int hk    = hv >> 1;

  const int qch0 = hk * 128;
  const int kch0 = 2048 + hk * 128;
  const int vch0 = 4096 + hv * 128 + chunk * NCOL;

  __shared__ __align__(16) float  xs[TILE][XSS];
  __shared__ __align__(16) float4 wc[272];
  __shared__ float  opT[256 * OTS];
  __shared__ float2 s_gb[TILE];
  __shared__ float  s_rq[TILE], s_rk[TILE];

  for (int i = tid; i < 272; i += 256) {
    int gch = (i < 128) ? (qch0 + i) : (i < 256) ? (kch0 + i - 128) : (vch0 + i - 256);
    wc[i] = *(const float4*)(win + (size_t)gch * 4);
  }

  const int lane = tid & 63;
  const int wv   = tid >> 6;
  const int rg   = lane & 15;
  const int col  = wv * 4 + (lane >> 4);
  const int rg4  = rg * 4;

  const float dtbv = dtb[hv];
  const float nA   = -__expf(alg[hv]);

  float S[8];
#pragma unroll
  for (int m = 0; m < 8; ++m) S[m] = 0.f;

  const float* xb  = xin + (size_t)bb * T_LEN * C_LEN;
  float*       op  = out + (size_t)bb * T_LEN * 4096 + hv * 128 + chunk * NCOL;
  float*       opw = &opT[(wv * 64 + lane) * OTS];

  for (int t0 = 0; t0 < T_LEN; t0 += TILE) {
    __syncthreads();
    for (int idx = tid; idx < TILE * 68; idx += 256) {
      int row = idx / 68;
      int c4  = idx - row * 68;
      int gch = (c4 < 32) ? (qch0 + c4 * 4)
              : (c4 < 64) ? (kch0 + (c4 - 32) * 4)
                          : (vch0 + (c4 - 64) * 4);
      int r = t0 + row - 3;
      const float* gp = xb + (size_t)r * C_LEN + gch;
      float4 a0 = (r     >= 0) ? *(const float4*)(gp)             : make_float4(0,0,0,0);
      float4 a1 = (r + 1 >= 0) ? *(const float4*)(gp + C_LEN)     : make_float4(0,0,0,0);
      float4 a2 = (r + 2 >= 0) ? *(const float4*)(gp + 2 * C_LEN) : make_float4(0,0,0,0);
      float4 a3 =                *(const float4*)(gp + 3 * C_LEN);
      float4 w0 = wc[c4 * 4], w1 = wc[c4 * 4 + 1], w2 = wc[c4 * 4 + 2], w3 = wc[c4 * 4 + 3];
      float4 o4;
      o4.x = a0.x * w0.x + a1.x * w0.y + a2.x * w0.z + a3.x * w0.w;
      o4.y = a0.y * w1.x + a1.y * w1.y + a2.y * w1.z + a3.y * w1.w;
      o4.z = a0.z * w2.x + a1.z * w2.y + a2.z * w2.z + a3.z * w2.w;
      o4.w = a0.w * w3.x + a1.w * w3.y + a2.w * w3.z + a3.w * w3.w;
      o4.x *= sigm(o4.x); o4.y *= sigm(o4.y); o4.z *= sigm(o4.z); o4.w *= sigm(o4.w);
      *(float4*)&xs[row][c4 * 4] = o4;
    }
    if (tid < TILE) {
      int tg = t0 + tid;
      size_t boff = ((size_t)bb * T_LEN + tg) * NHV + hv;
      float  bt = sigm(bin[boff]);
      float  x  = ain[boff] + dtbv;
      float  sp = fmaxf(x, 0.f) + log1pf(__expf(-fabsf(x)));
      s_gb[tid] = make_float2(__expf(nA * sp), bt);
    }
    __syncthreads();
    {
      int ttn = tid >> 3, l8 = tid & 7;
      float sq = 0.f, sk = 0.f;
#pragma unroll
      for (int m = 0; m < 16; ++m) {
        int cc = m * 8 + l8;
        float aq = xs[ttn][cc];
        float ak = xs[ttn][128 + cc];
        sq += aq * aq; sk += ak * ak;
      }
      sq += __shfl_xor(sq, 1); sq += __shfl_xor(sq, 2); sq += __shfl_xor(sq, 4);
      sk += __shfl_xor(sk, 1); sk += __shfl_xor(sk, 2); sk += __shfl_xor(sk, 4);
      if (l8 == 0) {
        s_rq[ttn] = rsqrtf(sq + 1e-6f) * 0.08838834764831845f;
        s_rk[ttn] = rsqrtf(sk + 1e-6f);
      }
    }
    __syncthreads();
    for (int idx = tid; idx < TILE * 64; idx += 256) {
      int row = idx >> 6, c4 = idx & 63;
      float f = (c4 < 32) ? s_rq[row] : s_rk[row];
      float4* p = (float4*)&xs[row][c4 * 4];
      float4 v = *p;
      v.x *= f; v.y *= f; v.z *= f; v.w *= f;
      *p = v;
    }
    __syncthreads();
#pragma unroll 2
    for (int tt = 0; tt < TILE; ++tt) {
      const float* xr = &xs[tt][0];
      float4 k0 = *(const float4*)(xr + 128 + rg4);
      float4 k1 = *(const float4*)(xr + 192 + rg4);
      float  vv = xr[256 + col];
      float4 q0 = *(const float4*)(xr +       rg4);
      float4 q1 = *(const float4*)(xr +  64 + rg4);

      float dk = k0.x*S[0] + k0.y*S[1] + k0.z*S[2] + k0.w*S[3]
               + k1.x*S[4] + k1.y*S[5] + k1.z*S[6] + k1.w*S[7];
      dk += __shfl_xor(dk, 1); dk += __shfl_xor(dk, 2);
      dk += __shfl_xor(dk, 4); dk += __shfl_xor(dk, 8);

      float2 gb    = s_gb[tt];
      float  eg    = gb.x;
      float  delta = (vv - eg * dk) * gb.y;

      S[0] = eg*S[0] + k0.x*delta;  S[1] = eg*S[1] + k0.y*delta;
      S[2] = eg*S[2] + k0.z*delta;  S[3] = eg*S[3] + k0.w*delta;
      S[4] = eg*S[4] + k1.x*delta;  S[5] = eg*S[5] + k1.y*delta;
      S[6] = eg*S[6] + k1.z*delta;  S[7] = eg*S[7] + k1.w*delta;

      float o = q0.x*S[0] + q0.y*S[1] + q0.z*S[2] + q0.w*S[3]
              + q1.x*S[4] + q1.y*S[5] + q1.z*S[6] + q1.w*S[7];
      opw[tt] = o;
    }
    __syncthreads();
    {
      int ttb = tid & 31, colb = tid >> 5;
#pragma unroll
      for (int it = 0; it < 2; ++it) {
        int cc = colb + it * 8;
        const float* pp = &opT[(cc * 16) * OTS + ttb];
        float s = 0.f;
#pragma unroll
        for (int i = 0; i < 16; ++i) s += pp[i * OTS];
        op[(size_t)(t0 + ttb) * 4096 + cc] = s;
      }
    }
  }
}

extern "C" void kernel_launch(void* const* d_in, const int* in_sizes, int n_in,
                              void* d_out, int out_size, void* d_ws, size_t ws_size,
                              hipStream_t stream) {
  (void)in_sizes; (void)n_in; (void)out_size;
  const float* xin = (const float*)d_in[0];
  const float* bin = (const float*)d_in[1];
  const float* ain = (const float*)d_in[2];
  const float* win = (const float*)d_in[3];
  const float* dtb = (const float*)d_in[4];
  const float* alg = (const float*)d_in[5];
  float* out = (float*)d_out;

  if (ws_size >= WS_NEED) {
    float*  xqk = (float*)d_ws;
    float2* xgb = (float2*)((char*)d_ws + WS_XQK_BYTES);
    k1_prep<<<dim3(1024), dim3(256), 0, stream>>>(xin, win, xqk);
    k1b_gate<<<dim3(512), dim3(256), 0, stream>>>(bin, ain, dtb, alg, xgb);
    k2_scan<<<dim3(1024), dim3(256), 0, stream>>>(xin, win, xqk, xgb, out);
  } else {
    gdn_fused<<<dim3(512), dim3(256), 0, stream>>>(xin, bin, ain, win, dtb, alg, out);
  }
}